// Round 3
// baseline (275.826 us; speedup 1.0000x reference)
//
#include <hip/hip_runtime.h>
#include <hip/hip_bf16.h>

// Single fused kernel: grid-wide MSE reduction with last-block finalization.
// Cross-XCD safety: partials stored/loaded with agent-scope atomics (coherent
// through the Infinity Cache); arrival counter is an ACQ_REL agent-scope add.
// Raw v_sqrt_f32 / v_rcp_f32 intrinsics (~1e-7 rel err) — threshold is 7.97e-2.

__device__ __forceinline__ void row6(float a, float b, float d,
                                     float& e1, float& e2,
                                     float& v1x, float& v1y,
                                     float& v2x, float& v2y) {
    float s = a + d;
    float disc2 = s * s - 4.0f * (a * d - b * b);
    float disc = __builtin_amdgcn_sqrtf(fmaxf(disc2, 0.0f));
    e1 = (s + disc) * 0.5f;
    e2 = (s - disc) * 0.5f;

    float mean = s * 0.5f;
    float hd = (a - d) * 0.5f;
    float r = __builtin_amdgcn_sqrtf(hd * hd + b * b);
    float lo = mean - r;
    float hi = mean + r;

    float vx = b;
    float vy = hi - a;
    float n = __builtin_amdgcn_sqrtf(vx * vx + vy * vy);
    bool safe = n > 1e-20f;
    float inv = safe ? __builtin_amdgcn_rcpf(n) : 0.0f;
    float vhx = safe ? vx * inv : 1.0f;
    float vhy = safe ? vy * inv : 0.0f;

    // argmin over [|lo - t|, |hi - t|]; strict < means tie -> index 0 (v_lo)
    bool hi1 = fabsf(hi - e1) < fabsf(lo - e1);
    bool hi2 = fabsf(hi - e2) < fabsf(lo - e2);

    v1x = hi1 ? vhx : -vhy;
    v1y = hi1 ? vhy : vhx;
    v2x = hi2 ? vhx : -vhy;
    v2y = hi2 ? vhy : vhx;
}

__device__ __forceinline__ void acc_row(float pa, float pb, float pd,
                                        float ta, float tb, float td,
                                        float& s0, float& s1, float& s2,
                                        float& s3, float& s4) {
    float pe1, pe2, p1x, p1y, p2x, p2y;
    float te1, te2, t1x, t1y, t2x, t2y;
    row6(pa, pb, pd, pe1, pe2, p1x, p1y, p2x, p2y);
    row6(ta, tb, td, te1, te2, t1x, t1y, t2x, t2y);
    float d1 = pe1 - te1, d2 = pe2 - te2;
    float a10 = p1x - t1x, a11 = p1y - t1y;
    float a20 = p2x - t2x, a21 = p2y - t2y;
    s0 += d1 * d1 + d2 * d2;
    s1 += a10 * a10;
    s2 += a11 * a11;
    s3 += a20 * a20;
    s4 += a21 * a21;
}

__global__ __launch_bounds__(256) void eigh_fused(const float* __restrict__ yp,
                                                  const float* __restrict__ yt,
                                                  const float* __restrict__ w,
                                                  float* __restrict__ out,
                                                  unsigned int* __restrict__ counter,
                                                  double* __restrict__ part,
                                                  int ngroups, int nrows, double invB) {
    double d0 = 0, d1 = 0, d2 = 0, d3 = 0, d4 = 0;
    const float4* yp4 = (const float4*)yp;
    const float4* yt4 = (const float4*)yt;
    int tid = blockIdx.x * blockDim.x + threadIdx.x;
    int stride = gridDim.x * blockDim.x;

    // 4 rows (= 12 floats = 3 float4) per iteration per array
    for (int g = tid; g < ngroups; g += stride) {
        float4 p0 = yp4[3 * g + 0];
        float4 p1 = yp4[3 * g + 1];
        float4 p2 = yp4[3 * g + 2];
        float4 t0 = yt4[3 * g + 0];
        float4 t1 = yt4[3 * g + 1];
        float4 t2 = yt4[3 * g + 2];
        float s0 = 0, s1 = 0, s2 = 0, s3 = 0, s4 = 0;
        acc_row(p0.x, p0.y, p0.z, t0.x, t0.y, t0.z, s0, s1, s2, s3, s4);
        acc_row(p0.w, p1.x, p1.y, t0.w, t1.x, t1.y, s0, s1, s2, s3, s4);
        acc_row(p1.z, p1.w, p2.x, t1.z, t1.w, t2.x, s0, s1, s2, s3, s4);
        acc_row(p2.y, p2.z, p2.w, t2.y, t2.z, t2.w, s0, s1, s2, s3, s4);
        d0 += (double)s0; d1 += (double)s1; d2 += (double)s2;
        d3 += (double)s3; d4 += (double)s4;
    }
    // scalar tail (nrows % 4 != 0 safety; no-op for B = 4194304)
    for (int rrow = 4 * ngroups + tid; rrow < nrows; rrow += stride) {
        float s0 = 0, s1 = 0, s2 = 0, s3 = 0, s4 = 0;
        acc_row(yp[3 * rrow], yp[3 * rrow + 1], yp[3 * rrow + 2],
                yt[3 * rrow], yt[3 * rrow + 1], yt[3 * rrow + 2],
                s0, s1, s2, s3, s4);
        d0 += (double)s0; d1 += (double)s1; d2 += (double)s2;
        d3 += (double)s3; d4 += (double)s4;
    }

    // wave (64-lane) shuffle reduction
    for (int off = 32; off > 0; off >>= 1) {
        d0 += __shfl_down(d0, off);
        d1 += __shfl_down(d1, off);
        d2 += __shfl_down(d2, off);
        d3 += __shfl_down(d3, off);
        d4 += __shfl_down(d4, off);
    }
    __shared__ double lds[4][5];
    __shared__ int is_last;
    int wave = threadIdx.x >> 6;
    int lane = threadIdx.x & 63;
    if (lane == 0) {
        lds[wave][0] = d0; lds[wave][1] = d1; lds[wave][2] = d2;
        lds[wave][3] = d3; lds[wave][4] = d4;
    }
    __syncthreads();
    if (threadIdx.x == 0) {
        double r0 = 0, r1 = 0, r2 = 0, r3 = 0, r4 = 0;
        for (int wv = 0; wv < 4; ++wv) {
            r0 += lds[wv][0]; r1 += lds[wv][1]; r2 += lds[wv][2];
            r3 += lds[wv][3]; r4 += lds[wv][4];
        }
        // Publish partials at agent scope (write-through to coherent point)
        double* o = part + 5 * (size_t)blockIdx.x;
        __hip_atomic_store(&o[0], r0, __ATOMIC_RELAXED, __HIP_MEMORY_SCOPE_AGENT);
        __hip_atomic_store(&o[1], r1, __ATOMIC_RELAXED, __HIP_MEMORY_SCOPE_AGENT);
        __hip_atomic_store(&o[2], r2, __ATOMIC_RELAXED, __HIP_MEMORY_SCOPE_AGENT);
        __hip_atomic_store(&o[3], r3, __ATOMIC_RELAXED, __HIP_MEMORY_SCOPE_AGENT);
        __hip_atomic_store(&o[4], r4, __ATOMIC_RELAXED, __HIP_MEMORY_SCOPE_AGENT);
        unsigned int old = __hip_atomic_fetch_add(counter, 1u, __ATOMIC_ACQ_REL,
                                                  __HIP_MEMORY_SCOPE_AGENT);
        is_last = (old == gridDim.x - 1) ? 1 : 0;
    }
    __syncthreads();
    if (!is_last) return;

    // Last block: fold all per-block partials and finalize.
    double f0 = 0, f1 = 0, f2 = 0, f3 = 0, f4 = 0;
    int nparts = gridDim.x;
    for (int i = threadIdx.x; i < nparts; i += 256) {
        const double* p = part + 5 * (size_t)i;
        f0 += __hip_atomic_load(&p[0], __ATOMIC_RELAXED, __HIP_MEMORY_SCOPE_AGENT);
        f1 += __hip_atomic_load(&p[1], __ATOMIC_RELAXED, __HIP_MEMORY_SCOPE_AGENT);
        f2 += __hip_atomic_load(&p[2], __ATOMIC_RELAXED, __HIP_MEMORY_SCOPE_AGENT);
        f3 += __hip_atomic_load(&p[3], __ATOMIC_RELAXED, __HIP_MEMORY_SCOPE_AGENT);
        f4 += __hip_atomic_load(&p[4], __ATOMIC_RELAXED, __HIP_MEMORY_SCOPE_AGENT);
    }
    for (int off = 32; off > 0; off >>= 1) {
        f0 += __shfl_down(f0, off);
        f1 += __shfl_down(f1, off);
        f2 += __shfl_down(f2, off);
        f3 += __shfl_down(f3, off);
        f4 += __shfl_down(f4, off);
    }
    __syncthreads();  // reuse lds[][] safely
    if (lane == 0) {
        lds[wave][0] = f0; lds[wave][1] = f1; lds[wave][2] = f2;
        lds[wave][3] = f3; lds[wave][4] = f4;
    }
    __syncthreads();
    if (threadIdx.x == 0) {
        double r0 = 0, r1 = 0, r2 = 0, r3 = 0, r4 = 0;
        for (int wv = 0; wv < 4; ++wv) {
            r0 += lds[wv][0]; r1 += lds[wv][1]; r2 += lds[wv][2];
            r3 += lds[wv][3]; r4 += lds[wv][4];
        }
        double evals_mse = r0 * invB * 0.5;  // mean over B*2 elements
        double mse = (double)w[0] * evals_mse
                   + (double)w[1] * (r1 * invB)
                   + (double)w[2] * (r2 * invB)
                   + (double)w[3] * (r3 * invB)
                   + (double)w[4] * (r4 * invB);
        out[0] = (float)mse;
    }
}

extern "C" void kernel_launch(void* const* d_in, const int* in_sizes, int n_in,
                              void* d_out, int out_size, void* d_ws, size_t ws_size,
                              hipStream_t stream) {
    const float* y_pred = (const float*)d_in[0];
    const float* y_true = (const float*)d_in[1];
    const float* weights = (const float*)d_in[2];
    float* out = (float*)d_out;

    int nrows = in_sizes[0] / 3;   // B = 4194304
    int ngroups = nrows / 4;

    // 4096 blocks x 256 threads = 1048576 threads -> exactly 1 group/thread at B=4M
    int blocks = 4096;
    size_t need = 64 + (size_t)blocks * 5 * sizeof(double);
    if (need > ws_size) blocks = (int)((ws_size - 64) / (5 * sizeof(double)));
    if (blocks < 1) blocks = 1;

    unsigned int* counter = (unsigned int*)d_ws;          // first 64 B: counter region
    double* part = (double*)((char*)d_ws + 64);           // then per-block partials

    hipMemsetAsync(d_ws, 0, 64, stream);                  // zero arrival counter
    eigh_fused<<<blocks, 256, 0, stream>>>(y_pred, y_true, weights, out,
                                           counter, part, ngroups, nrows,
                                           1.0 / (double)nrows);
}

// Round 4
// 123.938 us; speedup vs baseline: 2.2255x; 2.2255x over previous
//
#include <hip/hip_runtime.h>
#include <hip/hip_bf16.h>

// Two-kernel structure (partial-sums + tiny finalize). NOTE: a fused
// last-block-finalize variant with agent-scope atomics was tried and the
// cross-XCD coherence ops made the kernel 8x slower (171 us vs ~20 us) —
// the kernel boundary is the cheapest device-wide release/acquire.
//
// Per-row closed-form 2x2 symmetric eigendecomposition, mirroring the JAX ref:
//   analytic evals: disc = sqrt((a+d)^2 - 4(ad - b^2)); e1=(s+disc)/2 (larger), e2 smaller
//   eigh: r = sqrt(((a-d)/2)^2 + b^2); lam_lo/hi = mean -/+ r
//         v_hi = normalize(b, lam_hi - a) with n>1e-20 guard else (1,0); v_lo = (-vhy, vhx)
//   matching: idx = argmin(|[lam_lo, lam_hi] - target|), ties -> index 0 (v_lo)
// Raw v_sqrt_f32 / v_rcp_f32 intrinsics (~1e-7 rel err) — threshold is 7.97e-2.
__device__ __forceinline__ void row6(float a, float b, float d,
                                     float& e1, float& e2,
                                     float& v1x, float& v1y,
                                     float& v2x, float& v2y) {
    float s = a + d;
    float disc2 = s * s - 4.0f * (a * d - b * b);
    float disc = __builtin_amdgcn_sqrtf(fmaxf(disc2, 0.0f));
    e1 = (s + disc) * 0.5f;
    e2 = (s - disc) * 0.5f;

    float mean = s * 0.5f;
    float hd = (a - d) * 0.5f;
    float r = __builtin_amdgcn_sqrtf(hd * hd + b * b);
    float lo = mean - r;
    float hi = mean + r;

    float vx = b;
    float vy = hi - a;
    float n = __builtin_amdgcn_sqrtf(vx * vx + vy * vy);
    bool safe = n > 1e-20f;
    float inv = safe ? __builtin_amdgcn_rcpf(n) : 0.0f;
    float vhx = safe ? vx * inv : 1.0f;
    float vhy = safe ? vy * inv : 0.0f;

    // argmin over [|lo - t|, |hi - t|]; strict < means tie -> index 0 (v_lo)
    bool hi1 = fabsf(hi - e1) < fabsf(lo - e1);
    bool hi2 = fabsf(hi - e2) < fabsf(lo - e2);

    v1x = hi1 ? vhx : -vhy;
    v1y = hi1 ? vhy : vhx;
    v2x = hi2 ? vhx : -vhy;
    v2y = hi2 ? vhy : vhx;
}

// fp32 accumulation within a 4-row group (4 terms — exact enough), promoted to
// double at group granularity to keep f64 ops out of the hot path.
__device__ __forceinline__ void acc_row(float pa, float pb, float pd,
                                        float ta, float tb, float td,
                                        float& s0, float& s1, float& s2,
                                        float& s3, float& s4) {
    float pe1, pe2, p1x, p1y, p2x, p2y;
    float te1, te2, t1x, t1y, t2x, t2y;
    row6(pa, pb, pd, pe1, pe2, p1x, p1y, p2x, p2y);
    row6(ta, tb, td, te1, te2, t1x, t1y, t2x, t2y);
    float d1 = pe1 - te1, d2 = pe2 - te2;
    float a10 = p1x - t1x, a11 = p1y - t1y;
    float a20 = p2x - t2x, a21 = p2y - t2y;
    s0 += d1 * d1 + d2 * d2;
    s1 += a10 * a10;
    s2 += a11 * a11;
    s3 += a20 * a20;
    s4 += a21 * a21;
}

__global__ __launch_bounds__(256) void eigh_partial(const float* __restrict__ yp,
                                                    const float* __restrict__ yt,
                                                    double* __restrict__ part,
                                                    int ngroups, int nrows) {
    double d0 = 0, d1 = 0, d2 = 0, d3 = 0, d4 = 0;
    const float4* yp4 = (const float4*)yp;
    const float4* yt4 = (const float4*)yt;
    int tid = blockIdx.x * blockDim.x + threadIdx.x;
    int stride = gridDim.x * blockDim.x;

    // 4 rows (= 12 floats = 3 float4) per iteration per array
    for (int g = tid; g < ngroups; g += stride) {
        float4 p0 = yp4[3 * g + 0];
        float4 p1 = yp4[3 * g + 1];
        float4 p2 = yp4[3 * g + 2];
        float4 t0 = yt4[3 * g + 0];
        float4 t1 = yt4[3 * g + 1];
        float4 t2 = yt4[3 * g + 2];
        float s0 = 0, s1 = 0, s2 = 0, s3 = 0, s4 = 0;
        acc_row(p0.x, p0.y, p0.z, t0.x, t0.y, t0.z, s0, s1, s2, s3, s4);
        acc_row(p0.w, p1.x, p1.y, t0.w, t1.x, t1.y, s0, s1, s2, s3, s4);
        acc_row(p1.z, p1.w, p2.x, t1.z, t1.w, t2.x, s0, s1, s2, s3, s4);
        acc_row(p2.y, p2.z, p2.w, t2.y, t2.z, t2.w, s0, s1, s2, s3, s4);
        d0 += (double)s0; d1 += (double)s1; d2 += (double)s2;
        d3 += (double)s3; d4 += (double)s4;
    }
    // scalar tail (nrows % 4 != 0 safety; no-op for B = 4194304)
    for (int rrow = 4 * ngroups + tid; rrow < nrows; rrow += stride) {
        float s0 = 0, s1 = 0, s2 = 0, s3 = 0, s4 = 0;
        acc_row(yp[3 * rrow], yp[3 * rrow + 1], yp[3 * rrow + 2],
                yt[3 * rrow], yt[3 * rrow + 1], yt[3 * rrow + 2],
                s0, s1, s2, s3, s4);
        d0 += (double)s0; d1 += (double)s1; d2 += (double)s2;
        d3 += (double)s3; d4 += (double)s4;
    }

    // wave (64-lane) shuffle reduction
    for (int off = 32; off > 0; off >>= 1) {
        d0 += __shfl_down(d0, off);
        d1 += __shfl_down(d1, off);
        d2 += __shfl_down(d2, off);
        d3 += __shfl_down(d3, off);
        d4 += __shfl_down(d4, off);
    }
    __shared__ double lds[4][5];
    int wave = threadIdx.x >> 6;
    int lane = threadIdx.x & 63;
    if (lane == 0) {
        lds[wave][0] = d0; lds[wave][1] = d1; lds[wave][2] = d2;
        lds[wave][3] = d3; lds[wave][4] = d4;
    }
    __syncthreads();
    if (threadIdx.x == 0) {
        double r0 = 0, r1 = 0, r2 = 0, r3 = 0, r4 = 0;
        for (int w = 0; w < 4; ++w) {
            r0 += lds[w][0]; r1 += lds[w][1]; r2 += lds[w][2];
            r3 += lds[w][3]; r4 += lds[w][4];
        }
        double* o = part + 5 * (size_t)blockIdx.x;
        o[0] = r0; o[1] = r1; o[2] = r2; o[3] = r3; o[4] = r4;
    }
}

__global__ __launch_bounds__(256) void eigh_final(const double* __restrict__ part,
                                                  int nparts,
                                                  const float* __restrict__ w,
                                                  float* __restrict__ out,
                                                  double invB) {
    double s0 = 0, s1 = 0, s2 = 0, s3 = 0, s4 = 0;
    for (int i = threadIdx.x; i < nparts; i += 256) {
        const double* p = part + 5 * (size_t)i;
        s0 += p[0]; s1 += p[1]; s2 += p[2]; s3 += p[3]; s4 += p[4];
    }
    for (int off = 32; off > 0; off >>= 1) {
        s0 += __shfl_down(s0, off);
        s1 += __shfl_down(s1, off);
        s2 += __shfl_down(s2, off);
        s3 += __shfl_down(s3, off);
        s4 += __shfl_down(s4, off);
    }
    __shared__ double lds[4][5];
    int wave = threadIdx.x >> 6;
    int lane = threadIdx.x & 63;
    if (lane == 0) {
        lds[wave][0] = s0; lds[wave][1] = s1; lds[wave][2] = s2;
        lds[wave][3] = s3; lds[wave][4] = s4;
    }
    __syncthreads();
    if (threadIdx.x == 0) {
        double r0 = 0, r1 = 0, r2 = 0, r3 = 0, r4 = 0;
        for (int wv = 0; wv < 4; ++wv) {
            r0 += lds[wv][0]; r1 += lds[wv][1]; r2 += lds[wv][2];
            r3 += lds[wv][3]; r4 += lds[wv][4];
        }
        double evals_mse = r0 * invB * 0.5;  // mean over B*2 elements
        double mse = (double)w[0] * evals_mse
                   + (double)w[1] * (r1 * invB)
                   + (double)w[2] * (r2 * invB)
                   + (double)w[3] * (r3 * invB)
                   + (double)w[4] * (r4 * invB);
        out[0] = (float)mse;
    }
}

extern "C" void kernel_launch(void* const* d_in, const int* in_sizes, int n_in,
                              void* d_out, int out_size, void* d_ws, size_t ws_size,
                              hipStream_t stream) {
    const float* y_pred = (const float*)d_in[0];
    const float* y_true = (const float*)d_in[1];
    const float* weights = (const float*)d_in[2];
    float* out = (float*)d_out;

    int nrows = in_sizes[0] / 3;   // B = 4194304
    int ngroups = nrows / 4;

    // 4096 blocks x 256 threads = 1048576 threads -> exactly 1 group/thread at B=4M
    int blocks = 4096;
    size_t need = (size_t)blocks * 5 * sizeof(double);
    if (need > ws_size) blocks = (int)(ws_size / (5 * sizeof(double)));
    if (blocks < 1) blocks = 1;

    double* part = (double*)d_ws;

    eigh_partial<<<blocks, 256, 0, stream>>>(y_pred, y_true, part, ngroups, nrows);
    eigh_final<<<1, 256, 0, stream>>>(part, blocks, weights, out, 1.0 / (double)nrows);
}